// Round 12
// baseline (1018.856 us; speedup 1.0000x reference)
//
#include <hip/hip_runtime.h>

// ---------------------------------------------------------------------------
// LightGCN propagation: out = normalize(mean(emb, A emb, A^2 emb, A^3 emb))
// for two graphs (mashup: 100k nodes / 3.2M edges, api: 50k / 1.6M), D=64.
//
// Round-11 = round-10 with the compile fix (ext_vector v4f for the
// nontemporal float4 load; __builtin_nontemporal_load rejects
// HIP_vector_type).
//  pass1: blocks scan contiguous edge chunks once; items (val|col|rowoff, 8B)
//         binned into 512-row buckets via LDS 8-item carry buffers; global
//         flushes are full 8-item (64B) groups via per-bucket cursors ->
//         each tmp line written by one block in one phase (no RFO, amp~1).
//  pass2: sequential bucket re-read (b%8 -> XCD-pinned blocks), exact CSR
//         placement via row_pos cursors; scatter window 131KB = L2-resident.
//  Aliasing: tmp_m aliases the fp16 region, tmp_a aliases ev_m (pass2_a runs
//  before pass2_m); meta (row_pos/bsums/cursors) parked above tmp_m extent.
// ---------------------------------------------------------------------------

#define EMB_DIM 64
#define UNR 8
#define RPB_SH 9              // 512 rows per bucket
#define NBMAX 256
typedef unsigned long long ull;
typedef int v4i __attribute__((ext_vector_type(4)));
typedef float v4f __attribute__((ext_vector_type(4)));

static inline int cdiv(long long a, long long b) { return (int)((a + b - 1) / b); }

// ----------------------------- CSR build -----------------------------------

__global__ void k_zero2(int* __restrict__ pm, int nm_, int* __restrict__ pa,
                        int na_) {
    int i = blockIdx.x * blockDim.x + threadIdx.x;
    if (i < nm_) pm[i] = 0;
    else if (i < nm_ + na_) pa[i - nm_] = 0;
}

__global__ void k_hist2(const int* __restrict__ rm, int nem,
                        int* __restrict__ posm, const int* __restrict__ ra,
                        int nea, int* __restrict__ posa) {
    int nm4 = nem >> 2, na4 = nea >> 2;
    int i = blockIdx.x * blockDim.x + threadIdx.x;
    if (i < nm4) {
        v4i r = __builtin_nontemporal_load((const v4i*)rm + i);
        atomicAdd(&posm[r.x], 1);
        atomicAdd(&posm[r.y], 1);
        atomicAdd(&posm[r.z], 1);
        atomicAdd(&posm[r.w], 1);
    } else if (i < nm4 + na4) {
        v4i r = __builtin_nontemporal_load((const v4i*)ra + (i - nm4));
        atomicAdd(&posa[r.x], 1);
        atomicAdd(&posa[r.y], 1);
        atomicAdd(&posa[r.z], 1);
        atomicAdd(&posa[r.w], 1);
    } else if (i == nm4 + na4) {
        for (int t = nm4 << 2; t < nem; ++t) atomicAdd(&posm[rm[t]], 1);
        for (int t = na4 << 2; t < nea; ++t) atomicAdd(&posa[ra[t]], 1);
    }
}

#define SCAN_B 256
#define SCAN_E 1024

__global__ void k_scan1m(const int* __restrict__ inm, int nm_,
                         int* __restrict__ outm, int* __restrict__ bsm,
                         int nsbm, const int* __restrict__ ina, int na_,
                         int* __restrict__ outa, int* __restrict__ bsa) {
    bool is_m = (int)blockIdx.x < nsbm;
    const int* in = is_m ? inm : ina;
    int* out = is_m ? outm : outa;
    int* bsums = is_m ? bsm : bsa;
    int n = is_m ? nm_ : na_;
    int b = is_m ? blockIdx.x : blockIdx.x - nsbm;

    __shared__ int lds[SCAN_B];
    int t = threadIdx.x;
    int base = b * SCAN_E + t * 4;
    int v[4];
    int s = 0;
#pragma unroll
    for (int j = 0; j < 4; ++j) {
        v[j] = (base + j < n) ? in[base + j] : 0;
        s += v[j];
    }
    lds[t] = s;
    __syncthreads();
    for (int off = 1; off < SCAN_B; off <<= 1) {
        int x = (t >= off) ? lds[t - off] : 0;
        __syncthreads();
        lds[t] += x;
        __syncthreads();
    }
    int run = lds[t] - s;
    if (t == SCAN_B - 1) bsums[b] = lds[t];
#pragma unroll
    for (int j = 0; j < 4; ++j) {
        if (base + j < n) out[base + j] = run;
        run += v[j];
    }
}

__global__ void k_scan2m(int* __restrict__ bsm, int nbm, int* __restrict__ bsa,
                         int nba) {
    int* bsums = (blockIdx.x == 0) ? bsm : bsa;
    int nb = (blockIdx.x == 0) ? nbm : nba;
    __shared__ int lds[1024];
    int t = threadIdx.x;
    int v = (t < nb) ? bsums[t] : 0;
    lds[t] = v;
    __syncthreads();
    for (int off = 1; off < 1024; off <<= 1) {
        int x = (t >= off) ? lds[t - off] : 0;
        __syncthreads();
        lds[t] += x;
        __syncthreads();
    }
    if (t < nb) bsums[t] = lds[t] - v;
}

__global__ void k_scan3m(int* __restrict__ rpm, int* __restrict__ posm,
                         const int* __restrict__ bsm, int nm_, int nem,
                         int* __restrict__ rpa, int* __restrict__ posa,
                         const int* __restrict__ bsa, int na_, int nea) {
    int i = blockIdx.x * blockDim.x + threadIdx.x;
    if (i < nm_) {
        int p = rpm[i] + bsm[i >> 10];
        rpm[i] = p;
        posm[i] = p;
        if (i == 0) rpm[nm_] = nem;
    } else if (i < nm_ + na_) {
        int ii = i - nm_;
        int p = rpa[ii] + bsa[ii >> 10];
        rpa[ii] = p;
        posa[ii] = p;
        if (ii == 0) rpa[na_] = nea;
    }
}

// bucket cursors + bases: base[b] = (row_ptr[b<<9] & ~7) + 8*b  (8-aligned,
// monotone, non-overlapping; tmp has 8*NB slack).
__global__ void k_binit2(const int* __restrict__ rpm, int NBm,
                         int* __restrict__ curm, int* __restrict__ tbm,
                         const int* __restrict__ rpa, int NBa,
                         int* __restrict__ cura, int* __restrict__ tba) {
    int t = blockIdx.x * blockDim.x + threadIdx.x;
    if (t < NBm) {
        int base = (rpm[t << RPB_SH] & ~7) + 8 * t;
        curm[t] = base;
        tbm[t] = base;
    } else if (t < NBm + NBa) {
        int b = t - NBm;
        int base = (rpa[b << RPB_SH] & ~7) + 8 * b;
        cura[b] = base;
        tba[b] = base;
    }
}

// ---- pass 1: LDS-staged binning; full 8-item (64B) global flushes ----
__global__ __launch_bounds__(512) void k_pass1(
    const int* __restrict__ rm, const int* __restrict__ cm,
    const float* __restrict__ vm, int nem, int* __restrict__ curm,
    ull* __restrict__ tmpm, int NBm, const int* __restrict__ ra,
    const int* __restrict__ ca, const float* __restrict__ va, int nea,
    int* __restrict__ cura, ull* __restrict__ tmpa, int NBa, int bm) {
    __shared__ int l_cnt[NBMAX], l_tile[NBMAX], l_base[NBMAX], l_nf[NBMAX];
    __shared__ ull l_buf[NBMAX][8];

    const bool is_m = (int)blockIdx.x < bm;
    const int* rows = is_m ? rm : ra;
    const int* cols = is_m ? cm : ca;
    const float* vals = is_m ? vm : va;
    const int ne = is_m ? nem : nea;
    const int NB = is_m ? NBm : NBa;
    int* cursor = is_m ? curm : cura;
    ull* tmp = is_m ? tmpm : tmpa;
    const int nbk = is_m ? bm : (int)gridDim.x - bm;
    const int blk = is_m ? blockIdx.x : blockIdx.x - bm;

    int per = ((ne + nbk - 1) / nbk + 3) & ~3;
    int c0 = blk * per;
    int c1 = c0 + per;
    if (c1 > ne) c1 = ne;
    const int tid = threadIdx.x;

    for (int b = tid; b < NB; b += 512) l_cnt[b] = 0;

    for (int t0 = c0; t0 < c1; t0 += 2048) {
        for (int b = tid; b < NB; b += 512) l_tile[b] = 0;
        __syncthreads();

        int i0 = t0 + tid * 4;
        int bk[4];
        ull it[4];
        int ofs[4];
        bool act[4];
        if (i0 + 4 <= c1) {
            v4i r4 = __builtin_nontemporal_load((const v4i*)(rows + i0));
            v4i c4 = __builtin_nontemporal_load((const v4i*)(cols + i0));
            v4f v4 = __builtin_nontemporal_load((const v4f*)(vals + i0));
            int rr[4] = {r4.x, r4.y, r4.z, r4.w};
            int cc[4] = {c4.x, c4.y, c4.z, c4.w};
            float vv[4] = {v4.x, v4.y, v4.z, v4.w};
#pragma unroll
            for (int j = 0; j < 4; ++j) {
                act[j] = true;
                bk[j] = rr[j] >> RPB_SH;
                unsigned lo = (unsigned)cc[j] |
                              ((unsigned)(rr[j] & 511) << 17);
                it[j] = ((ull)__float_as_uint(vv[j]) << 32) | lo;
            }
        } else {
#pragma unroll
            for (int j = 0; j < 4; ++j) {
                int i = i0 + j;
                act[j] = i < c1;
                if (act[j]) {
                    int r = rows[i];
                    bk[j] = r >> RPB_SH;
                    unsigned lo = (unsigned)cols[i] |
                                  ((unsigned)(r & 511) << 17);
                    it[j] = ((ull)__float_as_uint(vals[i]) << 32) | lo;
                } else {
                    bk[j] = 0;
                }
            }
        }
#pragma unroll
        for (int j = 0; j < 4; ++j)
            if (act[j]) ofs[j] = atomicAdd(&l_tile[bk[j]], 1);
        __syncthreads();

        // plan: flush all complete 8-groups
        for (int b = tid; b < NB; b += 512) {
            int tot = l_cnt[b] + l_tile[b];
            int nf = tot & ~7;
            l_nf[b] = nf;
            if (nf > 0) l_base[b] = atomicAdd(&cursor[b], nf);
        }
        __syncthreads();

        // C1: owners flush previously staged items (ranks 0..old)
        for (int b = tid; b < NB; b += 512) {
            int nf = l_nf[b];
            if (nf > 0) {
                int old = l_cnt[b];
                int gb = l_base[b];
                for (int s = 0; s < old; ++s) tmp[gb + s] = l_buf[b][s];
            }
        }
        __syncthreads();

        // C2: place new items (direct if rank < nf, else carry buffer)
#pragma unroll
        for (int j = 0; j < 4; ++j) {
            if (act[j]) {
                int b = bk[j];
                int rank = l_cnt[b] + ofs[j];
                int nf = l_nf[b];
                if (rank < nf)
                    tmp[l_base[b] + rank] = it[j];
                else
                    l_buf[b][rank - nf] = it[j];
            }
        }
        __syncthreads();

        for (int b = tid; b < NB; b += 512)
            l_cnt[b] += l_tile[b] - l_nf[b];
        __syncthreads();
    }

    // final flush of <8 leftovers per bucket
    for (int b = tid; b < NB; b += 512) {
        int cnt = l_cnt[b];
        if (cnt > 0) {
            int gb = atomicAdd(&cursor[b], cnt);
            for (int s = 0; s < cnt; ++s) tmp[gb + s] = l_buf[b][s];
        }
    }
}

// ---- pass 2: sequential bucket read, exact CSR placement (L2 window) ----
__global__ void k_pass2(const ull* __restrict__ tmp,
                        const int* __restrict__ tb,
                        const int* __restrict__ rp, int NB, int n,
                        int* __restrict__ pos, ull* __restrict__ ev) {
    int p = blockIdx.x & 7;
    int bslot = blockIdx.x >> 3;
    int nslot = gridDim.x >> 3;
    for (int b = p; b < NB; b += 8) {
        int r0 = b << RPB_SH;
        int r1 = r0 + (1 << RPB_SH);
        if (r1 > n) r1 = n;
        int cnt = rp[r1] - rp[r0];
        int base = tb[b];
        for (int i = bslot * 256 + threadIdx.x; i < cnt; i += nslot * 256) {
            ull it = __builtin_nontemporal_load(tmp + base + i);
            unsigned lo = (unsigned)it;
            int row = r0 + (int)(lo >> 17);
            int ps = atomicAdd(&pos[row], 1);
            ev[ps] = (it & 0xFFFFFFFF00000000ull) | (ull)(lo & 0x1FFFFu);
        }
    }
}

// ------------------------ merged fp16 convert ------------------------------

__global__ void k_tohalf2(const float* __restrict__ sm, _Float16* __restrict__ dm,
                          int nm4, const float* __restrict__ sa,
                          _Float16* __restrict__ da, int na4) {
    int i = blockIdx.x * blockDim.x + threadIdx.x;
    const float* s;
    _Float16* d;
    int j;
    if (i < nm4) {
        s = sm; d = dm; j = i;
    } else if (i < nm4 + na4) {
        s = sa; d = da; j = i - nm4;
    } else {
        return;
    }
    float4 v = *reinterpret_cast<const float4*>(s + j * 4);
    _Float16 h[4] = {(_Float16)v.x, (_Float16)v.y, (_Float16)v.z,
                     (_Float16)v.w};
    *reinterpret_cast<ushort4*>(d + j * 4) = *reinterpret_cast<ushort4*>(h);
}

// ------------------------- quad-edge CSR SpMM ------------------------------

template <bool FIRST, bool LAST>
__device__ __forceinline__ void spmm_row(const ull* __restrict__ ev,
                                         const int* __restrict__ row_ptr,
                                         const _Float16* __restrict__ x,
                                         _Float16* __restrict__ nxt,
                                         float* __restrict__ acc,
                                         const float* __restrict__ emb,
                                         int row, int lane) {
    int q = lane >> 4;
    int sub = lane & 15;

    int s = row_ptr[row];
    int cnt = row_ptr[row + 1] - s;
    const ull* evr = ev + s;

    float a0[UNR], a1[UNR], a2[UNR], a3[UNR];
#pragma unroll
    for (int k = 0; k < UNR; ++k) {
        a0[k] = 0.f; a1[k] = 0.f; a2[k] = 0.f; a3[k] = 0.f;
    }

    int j = 0;
    for (; j + 4 * UNR <= cnt; j += 4 * UNR) {
        ull p[UNR];
#pragma unroll
        for (int k = 0; k < UNR; ++k)
            p[k] = __builtin_nontemporal_load(evr + j + 4 * k + q);
#pragma unroll
        for (int k = 0; k < UNR; ++k) {
            unsigned c = (unsigned)p[k];
            ull xd = *reinterpret_cast<const ull*>(
                x + ((size_t)c << 6) + (sub << 2));
            float v = __uint_as_float((unsigned)(p[k] >> 32));
            union { ull u; _Float16 f[4]; } cv;
            cv.u = xd;
            a0[k] = fmaf(v, (float)cv.f[0], a0[k]);
            a1[k] = fmaf(v, (float)cv.f[1], a1[k]);
            a2[k] = fmaf(v, (float)cv.f[2], a2[k]);
            a3[k] = fmaf(v, (float)cv.f[3], a3[k]);
        }
    }
    if (j < cnt) {
        ull p[UNR];
        bool act[UNR];
#pragma unroll
        for (int k = 0; k < UNR; ++k) {
            int slot = j + 4 * k + q;
            act[k] = slot < cnt;
            p[k] = act[k] ? __builtin_nontemporal_load(evr + slot) : 0ull;
        }
#pragma unroll
        for (int k = 0; k < UNR; ++k) {
            if (act[k]) {
                unsigned c = (unsigned)p[k];
                ull xd = *reinterpret_cast<const ull*>(
                    x + ((size_t)c << 6) + (sub << 2));
                float v = __uint_as_float((unsigned)(p[k] >> 32));
                union { ull u; _Float16 f[4]; } cv;
                cv.u = xd;
                a0[k] = fmaf(v, (float)cv.f[0], a0[k]);
                a1[k] = fmaf(v, (float)cv.f[1], a1[k]);
                a2[k] = fmaf(v, (float)cv.f[2], a2[k]);
                a3[k] = fmaf(v, (float)cv.f[3], a3[k]);
            }
        }
    }
    float t0 = 0.f, t1 = 0.f, t2 = 0.f, t3 = 0.f;
#pragma unroll
    for (int k = 0; k < UNR; ++k) {
        t0 += a0[k]; t1 += a1[k]; t2 += a2[k]; t3 += a3[k];
    }
    t0 += __shfl_xor(t0, 16); t0 += __shfl_xor(t0, 32);
    t1 += __shfl_xor(t1, 16); t1 += __shfl_xor(t1, 32);
    t2 += __shfl_xor(t2, 16); t2 += __shfl_xor(t2, 32);
    t3 += __shfl_xor(t3, 16); t3 += __shfl_xor(t3, 32);

    size_t base = ((size_t)row << 6) + (sub << 2);
    if (FIRST || !LAST) {
        if (q == 0) {
            float4 prev;
            if (FIRST)
                prev = *reinterpret_cast<const float4*>(emb + base);
            else
                prev = *reinterpret_cast<const float4*>(acc + base);
            float4 o = make_float4(prev.x + t0, prev.y + t1, prev.z + t2,
                                   prev.w + t3);
            *reinterpret_cast<float4*>(acc + base) = o;
            union { _Float16 f[4]; ull u; } h;
            h.f[0] = (_Float16)t0; h.f[1] = (_Float16)t1;
            h.f[2] = (_Float16)t2; h.f[3] = (_Float16)t3;
            *reinterpret_cast<ull*>(nxt + base) = h.u;
        }
    } else {
        float4 a2v = *reinterpret_cast<const float4*>(acc + base);
        float b0 = (a2v.x + t0) * 0.25f;
        float b1 = (a2v.y + t1) * 0.25f;
        float b2 = (a2v.z + t2) * 0.25f;
        float b3 = (a2v.w + t3) * 0.25f;
        float ss = b0 * b0 + b1 * b1 + b2 * b2 + b3 * b3;
#pragma unroll
        for (int off = 8; off; off >>= 1) ss += __shfl_xor(ss, off);
        float nrm = fmaxf(sqrtf(ss), 1e-12f);
        if (q == 0) {
            float4 o = make_float4(b0 / nrm, b1 / nrm, b2 / nrm, b3 / nrm);
            *reinterpret_cast<float4*>(acc + base) = o;
        }
    }
}

template <bool FIRST, bool LAST>
__global__ void k_spmm2(const ull* __restrict__ evm,
                        const int* __restrict__ rpm,
                        const _Float16* __restrict__ xm,
                        _Float16* __restrict__ nxm, float* __restrict__ accm,
                        const float* __restrict__ embm, int nm_,
                        const ull* __restrict__ eva,
                        const int* __restrict__ rpa,
                        const _Float16* __restrict__ xa,
                        _Float16* __restrict__ nxa, float* __restrict__ acca,
                        const float* __restrict__ emba, int na_) {
    int wid = (int)((blockIdx.x * blockDim.x + threadIdx.x) >> 6);
    int lane = threadIdx.x & 63;
    if (wid < nm_) {
        spmm_row<FIRST, LAST>(evm, rpm, xm, nxm, accm, embm, wid, lane);
    } else if (wid < nm_ + na_) {
        spmm_row<FIRST, LAST>(eva, rpa, xa, nxa, acca, emba, wid - nm_, lane);
    }
}

// ----------------------- fallback: atomic path -----------------------------

__global__ void k_copy2(const float4* __restrict__ src, float4* __restrict__ a,
                        float4* __restrict__ b, int n4) {
    int i = blockIdx.x * blockDim.x + threadIdx.x;
    if (i < n4) {
        float4 v = src[i];
        a[i] = v;
        b[i] = v;
    }
}

__global__ void k_zero(float4* __restrict__ p, int n4) {
    int i = blockIdx.x * blockDim.x + threadIdx.x;
    if (i < n4) p[i] = make_float4(0.f, 0.f, 0.f, 0.f);
}

__global__ void k_axpy(float4* __restrict__ acc, const float4* __restrict__ x,
                       int n4) {
    int i = blockIdx.x * blockDim.x + threadIdx.x;
    if (i < n4) {
        float4 a = acc[i];
        float4 v = x[i];
        a.x += v.x; a.y += v.y; a.z += v.z; a.w += v.w;
        acc[i] = a;
    }
}

__global__ void k_spmm_atomic(const int* __restrict__ rows,
                              const int* __restrict__ cols,
                              const float* __restrict__ vals,
                              const float* __restrict__ x,
                              float* __restrict__ y, int n_edges) {
    unsigned tid = blockIdx.x * blockDim.x + threadIdx.x;
    unsigned e = tid >> 4;
    if (e >= (unsigned)n_edges) return;
    int sub = tid & 15;
    int r = rows[e];
    int c = cols[e];
    float v = vals[e];
    const float4 xv =
        *reinterpret_cast<const float4*>(x + ((size_t)c << 6) + (sub << 2));
    float* yp = y + ((size_t)r << 6) + (sub << 2);
    unsafeAtomicAdd(yp + 0, v * xv.x);
    unsafeAtomicAdd(yp + 1, v * xv.y);
    unsafeAtomicAdd(yp + 2, v * xv.z);
    unsafeAtomicAdd(yp + 3, v * xv.w);
}

__global__ void k_normalize(float* __restrict__ out, int nrows) {
    int row = blockIdx.x * 4 + (threadIdx.x >> 6);
    if (row >= nrows) return;
    int lane = threadIdx.x & 63;
    size_t idx = ((size_t)row << 6) + lane;
    float v = out[idx] * 0.25f;
    float s = v * v;
#pragma unroll
    for (int off = 32; off; off >>= 1) s += __shfl_xor(s, off);
    float norm = fmaxf(sqrtf(s), 1e-12f);
    out[idx] = v / norm;
}

// ---------------------------------------------------------------------------

extern "C" void kernel_launch(void* const* d_in, const int* in_sizes, int n_in,
                              void* d_out, int out_size, void* d_ws,
                              size_t ws_size, hipStream_t stream) {
    const int* m_rows = (const int*)d_in[0];
    const int* m_cols = (const int*)d_in[1];
    const float* m_vals = (const float*)d_in[2];
    const int* a_rows = (const int*)d_in[3];
    const int* a_cols = (const int*)d_in[4];
    const float* a_vals = (const float*)d_in[5];
    const float* m_emb = (const float*)d_in[6];
    const float* a_emb = (const float*)d_in[7];

    int ne_m = in_sizes[0];
    int ne_a = in_sizes[3];
    int nm = in_sizes[6] / EMB_DIM;
    int na = in_sizes[7] / EMB_DIM;

    size_t elems_m = (size_t)nm * EMB_DIM;
    size_t elems_a = (size_t)na * EMB_DIM;
    float* out_m = (float*)d_out;
    float* out_a = out_m + elems_m;

    int NB_m = cdiv(nm, 1 << RPB_SH);
    int NB_a = cdiv(na, 1 << RPB_SH);

    // ws layout: ev_m | ev_a | U (fp16 x4 buffers; tmp_m + meta alias it) |
    // row_ptrs.  tmp_a aliases ev_m (consumed by pass2_a before pass2_m
    // writes ev_m).
    char* w = (char*)d_ws;
    ull* ev_m = (ull*)w;            w += (size_t)ne_m * sizeof(ull);
    ull* ev_a = (ull*)w;            w += (size_t)ne_a * sizeof(ull);
    char* U = w;                    w += (elems_m + elems_a) * 2 * sizeof(_Float16);
    int* row_ptr_m = (int*)w;       w += ((size_t)nm + 1) * sizeof(int);
    int* row_ptr_a = (int*)w;       w += ((size_t)na + 1) * sizeof(int);
    size_t need = (size_t)(w - (char*)d_ws);

    _Float16* x0h_m = (_Float16*)U;
    _Float16* buf_m = x0h_m + elems_m;
    _Float16* x0h_a = buf_m + elems_m;
    _Float16* buf_a = x0h_a + elems_a;

    // tmp_m aliases U[0 ..); extent = ne_m + 8*NBMAX items
    ull* tmp_m = (ull*)U;
    size_t tmpm_extent = ((size_t)ne_m + 8 * NBMAX) * sizeof(ull);
    // meta parked above tmp_m extent (consumed before tohalf2 writes there)
    char* meta = U + ((tmpm_extent + 1023) & ~(size_t)1023);
    int* row_pos_m = (int*)meta;
    int* row_pos_a = row_pos_m + nm;
    int* bsums_m = row_pos_a + na;
    int* bsums_a = bsums_m + 1024;
    int* cur_m = bsums_a + 1024;
    int* cur_a = cur_m + NBMAX;
    int* tb_m = cur_a + NBMAX;
    int* tb_a = tb_m + NBMAX;
    size_t meta_end = (size_t)((char*)(tb_a + NBMAX) - U);
    // tmp_a aliases ev_m
    ull* tmp_a = ev_m;
    size_t tmpa_extent = ((size_t)ne_a + 8 * NBMAX) * sizeof(ull);

    bool alias_ok =
        meta_end <= (elems_m + elems_a) * 2 * sizeof(_Float16) &&
        tmpa_extent <= (size_t)ne_m * sizeof(ull) &&
        NB_m <= NBMAX && NB_a <= NBMAX;

    if (ws_size >= need && alias_ok) {
        // ---- merged CSR build ----
        k_zero2<<<cdiv(nm + na, 256), 256, 0, stream>>>(row_pos_m, nm,
                                                        row_pos_a, na);
        k_hist2<<<cdiv((ne_m >> 2) + (ne_a >> 2) + 1, 256), 256, 0, stream>>>(
            m_rows, ne_m, row_pos_m, a_rows, ne_a, row_pos_a);
        int nsb_m = cdiv(nm, SCAN_E);
        int nsb_a = cdiv(na, SCAN_E);
        k_scan1m<<<nsb_m + nsb_a, SCAN_B, 0, stream>>>(
            row_pos_m, nm, row_ptr_m, bsums_m, nsb_m, row_pos_a, na,
            row_ptr_a, bsums_a);
        k_scan2m<<<2, 1024, 0, stream>>>(bsums_m, nsb_m, bsums_a, nsb_a);
        k_scan3m<<<cdiv(nm + na, 256), 256, 0, stream>>>(
            row_ptr_m, row_pos_m, bsums_m, nm, ne_m, row_ptr_a, row_pos_a,
            bsums_a, na, ne_a);
        k_binit2<<<cdiv(NB_m + NB_a, 256), 256, 0, stream>>>(
            row_ptr_m, NB_m, cur_m, tb_m, row_ptr_a, NB_a, cur_a, tb_a);
        // ---- two-pass radix scatter ----
        k_pass1<<<384, 512, 0, stream>>>(m_rows, m_cols, m_vals, ne_m, cur_m,
                                         tmp_m, NB_m, a_rows, a_cols, a_vals,
                                         ne_a, cur_a, tmp_a, NB_a, 256);
        // pass2_a FIRST (tmp_a aliases ev_m; must be consumed before pass2_m
        // writes ev_m)
        k_pass2<<<1024, 256, 0, stream>>>(tmp_a, tb_a, row_ptr_a, NB_a, na,
                                          row_pos_a, ev_a);
        k_pass2<<<2048, 256, 0, stream>>>(tmp_m, tb_m, row_ptr_m, NB_m, nm,
                                          row_pos_m, ev_m);
        // ---- merged fp16 source (overwrites tmp_m / meta aliases) ----
        int nm4 = (int)(elems_m / 4), na4 = (int)(elems_a / 4);
        k_tohalf2<<<cdiv(nm4 + na4, 256), 256, 0, stream>>>(
            m_emb, x0h_m, nm4, a_emb, x0h_a, na4);
        // ---- 3 merged SpMM layers ----
        int g = cdiv(nm + na, 4);
        k_spmm2<true, false><<<g, 256, 0, stream>>>(
            ev_m, row_ptr_m, x0h_m, buf_m, out_m, m_emb, nm,
            ev_a, row_ptr_a, x0h_a, buf_a, out_a, a_emb, na);
        k_spmm2<false, false><<<g, 256, 0, stream>>>(
            ev_m, row_ptr_m, buf_m, x0h_m, out_m, nullptr, nm,
            ev_a, row_ptr_a, buf_a, x0h_a, out_a, nullptr, na);
        k_spmm2<false, true><<<g, 256, 0, stream>>>(
            ev_m, row_ptr_m, x0h_m, nullptr, out_m, nullptr, nm,
            ev_a, row_ptr_a, x0h_a, nullptr, out_a, nullptr, na);
        return;
    }

    // Fallback: round-0 atomic path.
    float* fb0 = (float*)d_ws;
    float* fb1 = fb0 + elems_m;
    auto run_atomic = [&](const int* rows, const int* cols, const float* vals,
                          const float* emb, float* out, int nrows,
                          int nedges) {
        size_t n = (size_t)nrows * EMB_DIM;
        int n4 = (int)(n / 4);
        int eg = cdiv(n4, 256);
        k_copy2<<<eg, 256, 0, stream>>>((const float4*)emb, (float4*)out,
                                        (float4*)fb0, n4);
        float* cur = fb0;
        float* nxt = fb1;
        int spmm_grid = cdiv((long long)nedges * 16, 256);
        for (int l = 0; l < 3; ++l) {
            k_zero<<<eg, 256, 0, stream>>>((float4*)nxt, n4);
            k_spmm_atomic<<<spmm_grid, 256, 0, stream>>>(rows, cols, vals, cur,
                                                         nxt, nedges);
            k_axpy<<<eg, 256, 0, stream>>>((float4*)out, (const float4*)nxt,
                                           n4);
            float* t = cur; cur = nxt; nxt = t;
        }
        k_normalize<<<cdiv(nrows, 4), 256, 0, stream>>>(out, nrows);
    };
    run_atomic(m_rows, m_cols, m_vals, m_emb, out_m, nm, ne_m);
    run_atomic(a_rows, a_cols, a_vals, a_emb, out_a, na, ne_a);
}

// Round 13
// 797.276 us; speedup vs baseline: 1.2779x; 1.2779x over previous
//
#include <hip/hip_runtime.h>

// ---------------------------------------------------------------------------
// LightGCN propagation: out = normalize(mean(emb, A emb, A^2 emb, A^3 emb))
// for two graphs (mashup: 100k nodes / 3.2M edges, api: 50k / 1.6M), D=64.
//
// Round-12 = round-9 (951us: merged build, single-pass XCD scatter, merged
// quad-edge SpMM) with the GLOBAL-ATOMIC HISTOGRAM replaced by an
// LDS-PARTITIONED HISTOGRAM:
//  - rows split into 16384-row partitions (mashup NP=7, api NP=4); block
//    (p, slot) scans edge slice `slot` with NT loads, filters partition p,
//    counts into 32KB LDS of packed 16-bit counters (atomicAdd +1/+65536;
//    max count ~100 -> no carry).
//  - blocks dump LDS slabs to global with coalesced NT stores (no atomics);
//    k_histred sums slabs -> row counts. 4.8M global atomics -> 0.
//  - slabs alias ev_m/ev_a (dead until scatter); k_zero2 dropped.
// ---------------------------------------------------------------------------

#define EMB_DIM 64
#define UNR 8
#define PSH 14                 // 16384 rows per histogram partition
#define HS_M 48                // slices per mashup partition
#define HS_A 24                // slices per api partition
typedef unsigned long long ull;
typedef int v4i __attribute__((ext_vector_type(4)));

static inline int cdiv(long long a, long long b) { return (int)((a + b - 1) / b); }

// ---------------------- LDS-partitioned histogram --------------------------

__global__ __launch_bounds__(512) void k_histlds(
    const int* __restrict__ rm, int nem, int NPm, int Sm,
    unsigned* __restrict__ slabm, const int* __restrict__ ra, int nea,
    int NPa, int Sa, unsigned* __restrict__ slaba, int bm) {
    __shared__ unsigned h[8192];

    const bool is_m = (int)blockIdx.x < bm;
    const int* rows = is_m ? rm : ra;
    const int ne = is_m ? nem : nea;
    const int NP = is_m ? NPm : NPa;
    const int S = is_m ? Sm : Sa;
    unsigned* slab = is_m ? slabm : slaba;
    const int b = is_m ? blockIdx.x : blockIdx.x - bm;
    const int p = b % NP;
    const int slot = b / NP;
    const int tid = threadIdx.x;

    for (int i = tid; i < 8192; i += 512) h[i] = 0;
    __syncthreads();

    int chunk = ((ne + S - 1) / S + 3) & ~3;
    int c0 = slot * chunk;
    int c1 = c0 + chunk;
    if (c1 > ne) c1 = ne;

    for (int i0 = c0 + tid * 4; i0 < c1; i0 += 512 * 4) {
        if (i0 + 4 <= c1) {
            v4i r4 = __builtin_nontemporal_load((const v4i*)(rows + i0));
            int rr[4] = {r4.x, r4.y, r4.z, r4.w};
#pragma unroll
            for (int j = 0; j < 4; ++j) {
                int r = rr[j];
                if ((r >> PSH) == p)
                    atomicAdd(&h[(r & 16383) >> 1],
                              (r & 1) ? 65536u : 1u);
            }
        } else {
            for (int i = i0; i < c1; ++i) {
                int r = rows[i];
                if ((r >> PSH) == p)
                    atomicAdd(&h[(r & 16383) >> 1],
                              (r & 1) ? 65536u : 1u);
            }
        }
    }
    __syncthreads();

    unsigned* dst = slab + ((size_t)(slot * NP + p) << 13);
    for (int i = tid; i < 8192; i += 512)
        __builtin_nontemporal_store(h[i], dst + i);
}

// sum slabs -> per-row counts (writes row_pos; replaces zero+hist).
__global__ void k_histred(const unsigned* __restrict__ slabm, int NPm, int Sm,
                          int nm_, int* __restrict__ posm,
                          const unsigned* __restrict__ slaba, int NPa, int Sa,
                          int na_, int* __restrict__ posa) {
    int e = blockIdx.x * blockDim.x + threadIdx.x;
    int em = NPm << 13;
    const unsigned* slab;
    int NP, S, n, p, k;
    int* pos;
    if (e < em) {
        slab = slabm; NP = NPm; S = Sm; n = nm_; pos = posm;
        p = e >> 13; k = e & 8191;
    } else {
        e -= em;
        int ea = NPa << 13;
        if (e >= ea) return;
        slab = slaba; NP = NPa; S = Sa; n = na_; pos = posa;
        p = e >> 13; k = e & 8191;
    }
    unsigned s = 0;
    for (int slot = 0; slot < S; ++slot)
        s += slab[((size_t)(slot * NP + p) << 13) + k];
    int r0 = (p << PSH) + (k << 1);
    if (r0 < n) pos[r0] = (int)(s & 0xFFFFu);
    if (r0 + 1 < n) pos[r0 + 1] = (int)(s >> 16);
}

// ------------------------------- scans -------------------------------------

#define SCAN_B 256
#define SCAN_E 1024

__global__ void k_scan1m(const int* __restrict__ inm, int nm_,
                         int* __restrict__ outm, int* __restrict__ bsm,
                         int nsbm, const int* __restrict__ ina, int na_,
                         int* __restrict__ outa, int* __restrict__ bsa) {
    bool is_m = (int)blockIdx.x < nsbm;
    const int* in = is_m ? inm : ina;
    int* out = is_m ? outm : outa;
    int* bsums = is_m ? bsm : bsa;
    int n = is_m ? nm_ : na_;
    int b = is_m ? blockIdx.x : blockIdx.x - nsbm;

    __shared__ int lds[SCAN_B];
    int t = threadIdx.x;
    int base = b * SCAN_E + t * 4;
    int v[4];
    int s = 0;
#pragma unroll
    for (int j = 0; j < 4; ++j) {
        v[j] = (base + j < n) ? in[base + j] : 0;
        s += v[j];
    }
    lds[t] = s;
    __syncthreads();
    for (int off = 1; off < SCAN_B; off <<= 1) {
        int x = (t >= off) ? lds[t - off] : 0;
        __syncthreads();
        lds[t] += x;
        __syncthreads();
    }
    int run = lds[t] - s;
    if (t == SCAN_B - 1) bsums[b] = lds[t];
#pragma unroll
    for (int j = 0; j < 4; ++j) {
        if (base + j < n) out[base + j] = run;
        run += v[j];
    }
}

__global__ void k_scan2m(int* __restrict__ bsm, int nbm, int* __restrict__ bsa,
                         int nba) {
    int* bsums = (blockIdx.x == 0) ? bsm : bsa;
    int nb = (blockIdx.x == 0) ? nbm : nba;
    __shared__ int lds[1024];
    int t = threadIdx.x;
    int v = (t < nb) ? bsums[t] : 0;
    lds[t] = v;
    __syncthreads();
    for (int off = 1; off < 1024; off <<= 1) {
        int x = (t >= off) ? lds[t - off] : 0;
        __syncthreads();
        lds[t] += x;
        __syncthreads();
    }
    if (t < nb) bsums[t] = lds[t] - v;
}

__global__ void k_scan3m(int* __restrict__ rpm, int* __restrict__ posm,
                         const int* __restrict__ bsm, int nm_, int nem,
                         int* __restrict__ rpa, int* __restrict__ posa,
                         const int* __restrict__ bsa, int na_, int nea) {
    int i = blockIdx.x * blockDim.x + threadIdx.x;
    if (i < nm_) {
        int p = rpm[i] + bsm[i >> 10];
        rpm[i] = p;
        posm[i] = p;
        if (i == 0) rpm[nm_] = nem;
    } else if (i < nm_ + na_) {
        int ii = i - nm_;
        int p = rpa[ii] + bsa[ii >> 10];
        rpa[ii] = p;
        posa[ii] = p;
        if (ii == 0) rpa[na_] = nea;
    }
}

// Merged XCD-partitioned scatter: blocks [0,bm) -> mashup, [bm,grid) -> api.
__global__ void k_scatter2(const int* __restrict__ rm,
                           const int* __restrict__ cm,
                           const float* __restrict__ vm, int nem,
                           unsigned pmulm, int* __restrict__ posm,
                           ull* __restrict__ evm, const int* __restrict__ ra,
                           const int* __restrict__ ca,
                           const float* __restrict__ va, int nea,
                           unsigned pmula, int* __restrict__ posa,
                           ull* __restrict__ eva, int bm) {
    const int p = blockIdx.x & 7;
    const bool is_m = (int)blockIdx.x < bm;
    const int b = is_m ? blockIdx.x : blockIdx.x - bm;
    const int nslot = (is_m ? bm : (int)gridDim.x - bm) >> 3;
    const int bslot = b >> 3;

    const int* rows = is_m ? rm : ra;
    const int* cols = is_m ? cm : ca;
    const float* vals = is_m ? vm : va;
    const int ne = is_m ? nem : nea;
    const unsigned pmul = is_m ? pmulm : pmula;
    int* row_pos = is_m ? posm : posa;
    ull* ev = is_m ? evm : eva;

    const int nb4 = ne >> 2;
    const v4i* rows4 = (const v4i*)rows;

    for (int g = bslot * blockDim.x + threadIdx.x; g < nb4;
         g += nslot * blockDim.x) {
        v4i r4 = __builtin_nontemporal_load(rows4 + g);
        int base = g << 2;
#pragma unroll
        for (int k = 0; k < 4; ++k) {
            int r = (k == 0) ? r4.x : (k == 1) ? r4.y : (k == 2) ? r4.z : r4.w;
            if ((int)(((unsigned)r * pmul) >> 16) == p) {
                int i = base + k;
                float v = __builtin_nontemporal_load(vals + i);
                int c = __builtin_nontemporal_load(cols + i);
                ull pk = ((ull)__float_as_uint(v) << 32) | (unsigned)c;
                int pos = atomicAdd(&row_pos[r], 1);
                ev[pos] = pk;
            }
        }
    }
    if (bslot == 0 && threadIdx.x == 0) {
        for (int i = nb4 << 2; i < ne; ++i) {
            int r = rows[i];
            if ((int)(((unsigned)r * pmul) >> 16) == p) {
                ull pk = ((ull)__float_as_uint(vals[i]) << 32) |
                         (unsigned)cols[i];
                int pos = atomicAdd(&row_pos[r], 1);
                ev[pos] = pk;
            }
        }
    }
}

// ------------------------ merged fp16 convert ------------------------------

__global__ void k_tohalf2(const float* __restrict__ sm, _Float16* __restrict__ dm,
                          int nm4, const float* __restrict__ sa,
                          _Float16* __restrict__ da, int na4) {
    int i = blockIdx.x * blockDim.x + threadIdx.x;
    const float* s;
    _Float16* d;
    int j;
    if (i < nm4) {
        s = sm; d = dm; j = i;
    } else if (i < nm4 + na4) {
        s = sa; d = da; j = i - nm4;
    } else {
        return;
    }
    float4 v = *reinterpret_cast<const float4*>(s + j * 4);
    _Float16 h[4] = {(_Float16)v.x, (_Float16)v.y, (_Float16)v.z,
                     (_Float16)v.w};
    *reinterpret_cast<ushort4*>(d + j * 4) = *reinterpret_cast<ushort4*>(h);
}

// ------------------------- quad-edge CSR SpMM ------------------------------

template <bool FIRST, bool LAST>
__device__ __forceinline__ void spmm_row(const ull* __restrict__ ev,
                                         const int* __restrict__ row_ptr,
                                         const _Float16* __restrict__ x,
                                         _Float16* __restrict__ nxt,
                                         float* __restrict__ acc,
                                         const float* __restrict__ emb,
                                         int row, int lane) {
    int q = lane >> 4;
    int sub = lane & 15;

    int s = row_ptr[row];
    int cnt = row_ptr[row + 1] - s;
    const ull* evr = ev + s;

    float a0[UNR], a1[UNR], a2[UNR], a3[UNR];
#pragma unroll
    for (int k = 0; k < UNR; ++k) {
        a0[k] = 0.f; a1[k] = 0.f; a2[k] = 0.f; a3[k] = 0.f;
    }

    int j = 0;
    for (; j + 4 * UNR <= cnt; j += 4 * UNR) {
        ull p[UNR];
#pragma unroll
        for (int k = 0; k < UNR; ++k)
            p[k] = __builtin_nontemporal_load(evr + j + 4 * k + q);
#pragma unroll
        for (int k = 0; k < UNR; ++k) {
            unsigned c = (unsigned)p[k];
            ull xd = *reinterpret_cast<const ull*>(
                x + ((size_t)c << 6) + (sub << 2));
            float v = __uint_as_float((unsigned)(p[k] >> 32));
            union { ull u; _Float16 f[4]; } cv;
            cv.u = xd;
            a0[k] = fmaf(v, (float)cv.f[0], a0[k]);
            a1[k] = fmaf(v, (float)cv.f[1], a1[k]);
            a2[k] = fmaf(v, (float)cv.f[2], a2[k]);
            a3[k] = fmaf(v, (float)cv.f[3], a3[k]);
        }
    }
    if (j < cnt) {
        ull p[UNR];
        bool act[UNR];
#pragma unroll
        for (int k = 0; k < UNR; ++k) {
            int slot = j + 4 * k + q;
            act[k] = slot < cnt;
            p[k] = act[k] ? __builtin_nontemporal_load(evr + slot) : 0ull;
        }
#pragma unroll
        for (int k = 0; k < UNR; ++k) {
            if (act[k]) {
                unsigned c = (unsigned)p[k];
                ull xd = *reinterpret_cast<const ull*>(
                    x + ((size_t)c << 6) + (sub << 2));
                float v = __uint_as_float((unsigned)(p[k] >> 32));
                union { ull u; _Float16 f[4]; } cv;
                cv.u = xd;
                a0[k] = fmaf(v, (float)cv.f[0], a0[k]);
                a1[k] = fmaf(v, (float)cv.f[1], a1[k]);
                a2[k] = fmaf(v, (float)cv.f[2], a2[k]);
                a3[k] = fmaf(v, (float)cv.f[3], a3[k]);
            }
        }
    }
    float t0 = 0.f, t1 = 0.f, t2 = 0.f, t3 = 0.f;
#pragma unroll
    for (int k = 0; k < UNR; ++k) {
        t0 += a0[k]; t1 += a1[k]; t2 += a2[k]; t3 += a3[k];
    }
    t0 += __shfl_xor(t0, 16); t0 += __shfl_xor(t0, 32);
    t1 += __shfl_xor(t1, 16); t1 += __shfl_xor(t1, 32);
    t2 += __shfl_xor(t2, 16); t2 += __shfl_xor(t2, 32);
    t3 += __shfl_xor(t3, 16); t3 += __shfl_xor(t3, 32);

    size_t base = ((size_t)row << 6) + (sub << 2);
    if (FIRST || !LAST) {
        if (q == 0) {
            float4 prev;
            if (FIRST)
                prev = *reinterpret_cast<const float4*>(emb + base);
            else
                prev = *reinterpret_cast<const float4*>(acc + base);
            float4 o = make_float4(prev.x + t0, prev.y + t1, prev.z + t2,
                                   prev.w + t3);
            *reinterpret_cast<float4*>(acc + base) = o;
            union { _Float16 f[4]; ull u; } h;
            h.f[0] = (_Float16)t0; h.f[1] = (_Float16)t1;
            h.f[2] = (_Float16)t2; h.f[3] = (_Float16)t3;
            *reinterpret_cast<ull*>(nxt + base) = h.u;
        }
    } else {
        float4 a2v = *reinterpret_cast<const float4*>(acc + base);
        float b0 = (a2v.x + t0) * 0.25f;
        float b1 = (a2v.y + t1) * 0.25f;
        float b2 = (a2v.z + t2) * 0.25f;
        float b3 = (a2v.w + t3) * 0.25f;
        float ss = b0 * b0 + b1 * b1 + b2 * b2 + b3 * b3;
#pragma unroll
        for (int off = 8; off; off >>= 1) ss += __shfl_xor(ss, off);
        float nrm = fmaxf(sqrtf(ss), 1e-12f);
        if (q == 0) {
            float4 o = make_float4(b0 / nrm, b1 / nrm, b2 / nrm, b3 / nrm);
            *reinterpret_cast<float4*>(acc + base) = o;
        }
    }
}

template <bool FIRST, bool LAST>
__global__ void k_spmm2(const ull* __restrict__ evm,
                        const int* __restrict__ rpm,
                        const _Float16* __restrict__ xm,
                        _Float16* __restrict__ nxm, float* __restrict__ accm,
                        const float* __restrict__ embm, int nm_,
                        const ull* __restrict__ eva,
                        const int* __restrict__ rpa,
                        const _Float16* __restrict__ xa,
                        _Float16* __restrict__ nxa, float* __restrict__ acca,
                        const float* __restrict__ emba, int na_) {
    int wid = (int)((blockIdx.x * blockDim.x + threadIdx.x) >> 6);
    int lane = threadIdx.x & 63;
    if (wid < nm_) {
        spmm_row<FIRST, LAST>(evm, rpm, xm, nxm, accm, embm, wid, lane);
    } else if (wid < nm_ + na_) {
        spmm_row<FIRST, LAST>(eva, rpa, xa, nxa, acca, emba, wid - nm_, lane);
    }
}

// ----------------------- fallback: atomic path -----------------------------

__global__ void k_copy2(const float4* __restrict__ src, float4* __restrict__ a,
                        float4* __restrict__ b, int n4) {
    int i = blockIdx.x * blockDim.x + threadIdx.x;
    if (i < n4) {
        float4 v = src[i];
        a[i] = v;
        b[i] = v;
    }
}

__global__ void k_zero(float4* __restrict__ p, int n4) {
    int i = blockIdx.x * blockDim.x + threadIdx.x;
    if (i < n4) p[i] = make_float4(0.f, 0.f, 0.f, 0.f);
}

__global__ void k_axpy(float4* __restrict__ acc, const float4* __restrict__ x,
                       int n4) {
    int i = blockIdx.x * blockDim.x + threadIdx.x;
    if (i < n4) {
        float4 a = acc[i];
        float4 v = x[i];
        a.x += v.x; a.y += v.y; a.z += v.z; a.w += v.w;
        acc[i] = a;
    }
}

__global__ void k_spmm_atomic(const int* __restrict__ rows,
                              const int* __restrict__ cols,
                              const float* __restrict__ vals,
                              const float* __restrict__ x,
                              float* __restrict__ y, int n_edges) {
    unsigned tid = blockIdx.x * blockDim.x + threadIdx.x;
    unsigned e = tid >> 4;
    if (e >= (unsigned)n_edges) return;
    int sub = tid & 15;
    int r = rows[e];
    int c = cols[e];
    float v = vals[e];
    const float4 xv =
        *reinterpret_cast<const float4*>(x + ((size_t)c << 6) + (sub << 2));
    float* yp = y + ((size_t)r << 6) + (sub << 2);
    unsafeAtomicAdd(yp + 0, v * xv.x);
    unsafeAtomicAdd(yp + 1, v * xv.y);
    unsafeAtomicAdd(yp + 2, v * xv.z);
    unsafeAtomicAdd(yp + 3, v * xv.w);
}

__global__ void k_normalize(float* __restrict__ out, int nrows) {
    int row = blockIdx.x * 4 + (threadIdx.x >> 6);
    if (row >= nrows) return;
    int lane = threadIdx.x & 63;
    size_t idx = ((size_t)row << 6) + lane;
    float v = out[idx] * 0.25f;
    float s = v * v;
#pragma unroll
    for (int off = 32; off; off >>= 1) s += __shfl_xor(s, off);
    float norm = fmaxf(sqrtf(s), 1e-12f);
    out[idx] = v / norm;
}

// ---------------------------------------------------------------------------

extern "C" void kernel_launch(void* const* d_in, const int* in_sizes, int n_in,
                              void* d_out, int out_size, void* d_ws,
                              size_t ws_size, hipStream_t stream) {
    const int* m_rows = (const int*)d_in[0];
    const int* m_cols = (const int*)d_in[1];
    const float* m_vals = (const float*)d_in[2];
    const int* a_rows = (const int*)d_in[3];
    const int* a_cols = (const int*)d_in[4];
    const float* a_vals = (const float*)d_in[5];
    const float* m_emb = (const float*)d_in[6];
    const float* a_emb = (const float*)d_in[7];

    int ne_m = in_sizes[0];
    int ne_a = in_sizes[3];
    int nm = in_sizes[6] / EMB_DIM;
    int na = in_sizes[7] / EMB_DIM;

    size_t elems_m = (size_t)nm * EMB_DIM;
    size_t elems_a = (size_t)na * EMB_DIM;
    float* out_m = (float*)d_out;
    float* out_a = out_m + elems_m;

    int NP_m = cdiv(nm, 1 << PSH);
    int NP_a = cdiv(na, 1 << PSH);

    // ws layout: both graphs' ev + fp16 ping-pongs resident (77.4MB).
    char* w = (char*)d_ws;
    ull* ev_m = (ull*)w;            w += (size_t)ne_m * sizeof(ull);
    ull* ev_a = (ull*)w;            w += (size_t)ne_a * sizeof(ull);
    _Float16* x0h_m = (_Float16*)w; w += elems_m * sizeof(_Float16);
    _Float16* buf_m = (_Float16*)w; w += elems_m * sizeof(_Float16);
    _Float16* x0h_a = (_Float16*)w; w += elems_a * sizeof(_Float16);
    _Float16* buf_a = (_Float16*)w; w += elems_a * sizeof(_Float16);
    int* row_ptr_m = (int*)w;       w += ((size_t)nm + 1) * sizeof(int);
    int* row_ptr_a = (int*)w;       w += ((size_t)na + 1) * sizeof(int);
    size_t need = (size_t)(w - (char*)d_ws);

    // aliases inside x0h_m region (dead until after scatter; tohalf runs later)
    int* row_pos_m = (int*)x0h_m;
    int* row_pos_a = row_pos_m + nm;
    int* bsums_m = row_pos_a + na;
    int* bsums_a = bsums_m + 1024;
    bool alias_ok = ((size_t)nm + na + 2048) * sizeof(int) <=
                    elems_m * sizeof(_Float16);

    // hist slabs alias ev regions (dead before scatter writes ev)
    unsigned* slab_m = (unsigned*)ev_m;
    unsigned* slab_a = (unsigned*)ev_a;
    size_t slabm_bytes = (size_t)HS_M * NP_m * 8192 * sizeof(unsigned);
    size_t slaba_bytes = (size_t)HS_A * NP_a * 8192 * sizeof(unsigned);
    alias_ok = alias_ok && slabm_bytes <= (size_t)ne_m * sizeof(ull) &&
               slaba_bytes <= (size_t)ne_a * sizeof(ull) && NP_m <= 16 &&
               NP_a <= 16;

    if (ws_size >= need && alias_ok) {
        // ---- LDS-partitioned histogram (no global atomics) ----
        int hb_m = HS_M * NP_m;
        int hb_a = HS_A * NP_a;
        k_histlds<<<hb_m + hb_a, 512, 0, stream>>>(m_rows, ne_m, NP_m, HS_M,
                                                   slab_m, a_rows, ne_a, NP_a,
                                                   HS_A, slab_a, hb_m);
        int red_threads = (NP_m + NP_a) * 8192;
        k_histred<<<cdiv(red_threads, 256), 256, 0, stream>>>(
            slab_m, NP_m, HS_M, nm, row_pos_m, slab_a, NP_a, HS_A, na,
            row_pos_a);
        // ---- scans ----
        int nsb_m = cdiv(nm, SCAN_E);
        int nsb_a = cdiv(na, SCAN_E);
        k_scan1m<<<nsb_m + nsb_a, SCAN_B, 0, stream>>>(
            row_pos_m, nm, row_ptr_m, bsums_m, nsb_m, row_pos_a, na,
            row_ptr_a, bsums_a);
        k_scan2m<<<2, 1024, 0, stream>>>(bsums_m, nsb_m, bsums_a, nsb_a);
        k_scan3m<<<cdiv(nm + na, 256), 256, 0, stream>>>(
            row_ptr_m, row_pos_m, bsums_m, nm, ne_m, row_ptr_a, row_pos_a,
            bsums_a, na, ne_a);
        // ---- single-pass XCD-partitioned scatter ----
        unsigned pmul_m = (unsigned)(((unsigned long long)8 << 16) / (unsigned)nm);
        unsigned pmul_a = (unsigned)(((unsigned long long)8 << 16) / (unsigned)na);
        k_scatter2<<<2048, 256, 0, stream>>>(m_rows, m_cols, m_vals, ne_m,
                                             pmul_m, row_pos_m, ev_m, a_rows,
                                             a_cols, a_vals, ne_a, pmul_a,
                                             row_pos_a, ev_a, 1408);
        // ---- merged fp16 source (overwrites row_pos/bsums aliases) ----
        int nm4 = (int)(elems_m / 4), na4 = (int)(elems_a / 4);
        k_tohalf2<<<cdiv(nm4 + na4, 256), 256, 0, stream>>>(
            m_emb, x0h_m, nm4, a_emb, x0h_a, na4);
        // ---- 3 merged SpMM layers ----
        int g = cdiv(nm + na, 4);
        k_spmm2<true, false><<<g, 256, 0, stream>>>(
            ev_m, row_ptr_m, x0h_m, buf_m, out_m, m_emb, nm,
            ev_a, row_ptr_a, x0h_a, buf_a, out_a, a_emb, na);
        k_spmm2<false, false><<<g, 256, 0, stream>>>(
            ev_m, row_ptr_m, buf_m, x0h_m, out_m, nullptr, nm,
            ev_a, row_ptr_a, buf_a, x0h_a, out_a, nullptr, na);
        k_spmm2<false, true><<<g, 256, 0, stream>>>(
            ev_m, row_ptr_m, x0h_m, nullptr, out_m, nullptr, nm,
            ev_a, row_ptr_a, x0h_a, nullptr, out_a, nullptr, na);
        return;
    }

    // Fallback: round-0 atomic path.
    float* fb0 = (float*)d_ws;
    float* fb1 = fb0 + elems_m;
    auto run_atomic = [&](const int* rows, const int* cols, const float* vals,
                          const float* emb, float* out, int nrows,
                          int nedges) {
        size_t n = (size_t)nrows * EMB_DIM;
        int n4 = (int)(n / 4);
        int eg = cdiv(n4, 256);
        k_copy2<<<eg, 256, 0, stream>>>((const float4*)emb, (float4*)out,
                                        (float4*)fb0, n4);
        float* cur = fb0;
        float* nxt = fb1;
        int spmm_grid = cdiv((long long)nedges * 16, 256);
        for (int l = 0; l < 3; ++l) {
            k_zero<<<eg, 256, 0, stream>>>((float4*)nxt, n4);
            k_spmm_atomic<<<spmm_grid, 256, 0, stream>>>(rows, cols, vals, cur,
                                                         nxt, nedges);
            k_axpy<<<eg, 256, 0, stream>>>((float4*)out, (const float4*)nxt,
                                           n4);
            float* t = cur; cur = nxt; nxt = t;
        }
        k_normalize<<<cdiv(nrows, 4), 256, 0, stream>>>(out, nrows);
    };
    run_atomic(m_rows, m_cols, m_vals, m_emb, out_m, nm, ne_m);
    run_atomic(a_rows, a_cols, a_vals, a_emb, out_a, na, ne_a);
}